// Round 6
// baseline (2241.395 us; speedup 1.0000x reference)
//
#include <hip/hip_runtime.h>
#include <hip/hip_fp16.h>
#include <stdint.h>

#define Bsz 64
#define Tsz 1024
#define Dsz 256
#define UNITSn 256
#define Zdim 1024      // 4*UNITS

typedef _Float16 f16x8  __attribute__((ext_vector_type(8)));
typedef float    f32x4  __attribute__((ext_vector_type(4)));

// Guaranteed single-instruction 2-MAC f16 dot with f32 accumulate.
__device__ __forceinline__ float dot2acc(uint32_t w, uint32_t h, float acc) {
  asm("v_dot2_f32_f16 %0, %1, %2, %0" : "+v"(acc) : "v"(w), "v"(h));
  return acc;
}

__device__ __forceinline__ float dot4(const uint4& w, const uint4& h, float acc) {
  acc = dot2acc(w.x, h.x, acc); acc = dot2acc(w.y, h.y, acc);
  acc = dot2acc(w.z, h.z, acc); acc = dot2acc(w.w, h.w, acc);
  return acc;
}

__device__ __forceinline__ float sigm(float x)   { return 1.0f / (1.0f + __expf(-x)); }
__device__ __forceinline__ float tanh_f(float x) { return 1.0f - 2.0f / (__expf(2.0f * x) + 1.0f); }

// U[256][1024] fp32 -> UT[1024][256] f16 (transposed, k-contiguous)
__global__ __launch_bounds__(256) void convert_u(const float* __restrict__ U,
                                                 _Float16* __restrict__ UT) {
  int i = blockIdx.x * 256 + threadIdx.x;   // 262144
  int n = i >> 8, k = i & 255;
  UT[i] = (_Float16)U[(size_t)k * Zdim + n];
}

// W[256][1024] fp32 -> f16-pair layouts for lstm v6 (1024 threads, quarter-K).
// Thread t (q=t>>8, u=t&255), gate g: col=g*256+u, k2 = q*32 + j*4 + e, j=0..7.
//  slot<16 : Wop [(g*4+j)*1024+t]   j=0..3   (VGPR, opaque)
//  16..23  : Wlds[(jj*4+g)*1024+t]  j=4+jj   (LDS)
//  24..31  : Wstr[(jj*4+g)*1024+t]  j=6+jj   (L2 stream)
__global__ __launch_bounds__(256) void convert_w6(const float* __restrict__ W,
                                                  uint4* __restrict__ Wop,
                                                  uint4* __restrict__ Wlds,
                                                  uint4* __restrict__ Wstr) {
  int i = blockIdx.x * 256 + threadIdx.x;   // 32768 uint4
  if (i >= 32768) return;
  int slot = i >> 10, t = i & 1023;
  int q = t >> 8, u = t & 255;
  int g, j, outIdx;
  uint4* dst;
  if (slot < 16)      { g = slot >> 2;      j = slot & 3;            dst = Wop;  outIdx = slot * 1024 + t; }
  else if (slot < 24) { int cl = slot - 16; g = cl & 3; j = 4 + (cl >> 2); dst = Wlds; outIdx = cl * 1024 + t; }
  else                { int ss = slot - 24; g = ss & 3; j = 6 + (ss >> 2); dst = Wstr; outIdx = ss * 1024 + t; }
  int col = g * 256 + u;
  int kbase = q * 32 + j * 4;
  uint32_t d[4];
#pragma unroll
  for (int e = 0; e < 4; e++) {
    int k2 = kbase + e;
    float w0 = W[(size_t)(2 * k2) * Zdim + col];
    float w1 = W[(size_t)(2 * k2 + 1) * Zdim + col];
    __half2 p = __floats2half2_rn(w0, w1);
    d[e] = __builtin_bit_cast(uint32_t, p);
  }
  dst[outIdx] = make_uint4(d[0], d[1], d[2], d[3]);
}

// xz[(tloc*64+b)*1024+n] = x[b][t][:] @ U[:,n] + bias[n] via f16 MFMA.
__global__ __launch_bounds__(256) void proj_mfma(
    const float* __restrict__ x, const _Float16* __restrict__ UT,
    const float* __restrict__ bias, float* __restrict__ xz, int t0) {
  __shared__ _Float16 Ax[64][40];
  __shared__ _Float16 Ux[256][40];
  const int tid  = threadIdx.x;
  const int w    = tid >> 6, lane = tid & 63;
  const int lr   = lane & 15, kg = lane >> 4;
  const int n0   = blockIdx.x * 256;
  const int tloc = blockIdx.y;
  const int t    = t0 + tloc;
  const int arow = tid >> 2, ak = (tid & 3) * 8;

  f32x4 acc[4][4];
#pragma unroll
  for (int mi = 0; mi < 4; mi++)
#pragma unroll
    for (int ni = 0; ni < 4; ni++) acc[mi][ni] = f32x4{0.f, 0.f, 0.f, 0.f};

  for (int k0 = 0; k0 < Dsz; k0 += 32) {
    const float* xp = x + ((size_t)arow * Tsz + t) * Dsz + k0 + ak;
    float4 p0 = *(const float4*)xp;
    float4 p1 = *(const float4*)(xp + 4);
    const _Float16* up = UT + (size_t)(n0 + tid) * Dsz + k0;
    f16x8 u0 = *(const f16x8*)up;
    f16x8 u1 = *(const f16x8*)(up + 8);
    f16x8 u2 = *(const f16x8*)(up + 16);
    f16x8 u3 = *(const f16x8*)(up + 24);
    __syncthreads();
    f16x8 a8;
    a8[0] = (_Float16)p0.x; a8[1] = (_Float16)p0.y;
    a8[2] = (_Float16)p0.z; a8[3] = (_Float16)p0.w;
    a8[4] = (_Float16)p1.x; a8[5] = (_Float16)p1.y;
    a8[6] = (_Float16)p1.z; a8[7] = (_Float16)p1.w;
    *(f16x8*)&Ax[arow][ak] = a8;
    *(f16x8*)&Ux[tid][0]  = u0;
    *(f16x8*)&Ux[tid][8]  = u1;
    *(f16x8*)&Ux[tid][16] = u2;
    *(f16x8*)&Ux[tid][24] = u3;
    __syncthreads();
    f16x8 af[4], uf[4];
#pragma unroll
    for (int mi = 0; mi < 4; mi++) af[mi] = *(const f16x8*)&Ax[mi * 16 + lr][kg * 8];
#pragma unroll
    for (int ni = 0; ni < 4; ni++) uf[ni] = *(const f16x8*)&Ux[w * 64 + ni * 16 + lr][kg * 8];
#pragma unroll
    for (int mi = 0; mi < 4; mi++)
#pragma unroll
      for (int ni = 0; ni < 4; ni++)
        acc[mi][ni] = __builtin_amdgcn_mfma_f32_16x16x32_f16(af[mi], uf[ni],
                                                             acc[mi][ni], 0, 0, 0);
  }
#pragma unroll
  for (int ni = 0; ni < 4; ni++) {
    int col = n0 + w * 64 + ni * 16 + lr;
    float bs = bias[col];
#pragma unroll
    for (int mi = 0; mi < 4; mi++) {
      f32x4 v = acc[mi][ni];
#pragma unroll
      for (int r = 0; r < 4; r++) {
        int brow = mi * 16 + kg * 4 + r;
        xz[((size_t)tloc * 64 + brow) * Zdim + col] = v[r] + bs;
      }
    }
  }
}

// One WG (1024 thr = 16 waves = 4 waves/SIMD) per batch. Thread (q=tid>>8,
// u=tid&255): quarter-K partials for gate cols {g*256+u}. W/thread = 32 uint4:
// 16 opaque-VGPR (256KB/CU) + 8 LDS (128KB/CU) + 8 L2-stream (128KB/step).
__global__ __launch_bounds__(1024)
__attribute__((amdgpu_waves_per_eu(4, 4)))
void lstm_chunk(const float* __restrict__ xz, const uint4* __restrict__ Wop,
                const uint4* __restrict__ WldsBuf, const uint4* __restrict__ Wstr,
                float* __restrict__ out, uint4* __restrict__ h_state,
                float* __restrict__ c_state, int t0, int Tc, int n_out) {
  extern __shared__ uint4 smem4[];
  uint4*  Wl = smem4;                           // 8*1024 uint4 = 128 KB
  uint4*  hq = smem4 + 8192;                    // [2][32] uint4 = 1 KB
  float4* pp = (float4*)(smem4 + 8192 + 64);    // [3][256] float4 = 12 KB

  const int tid = threadIdx.x;
  const int b   = blockIdx.x;
  const int q   = tid >> 8, u = tid & 255;

  uint4 wop[16];
#pragma unroll
  for (int j = 0; j < 16; j++) wop[j] = Wop[(size_t)j * 1024 + tid];
#pragma unroll
  for (int j = 0; j < 16; j++)
    asm volatile("" : "+v"(wop[j].x), "+v"(wop[j].y), "+v"(wop[j].z), "+v"(wop[j].w));
#pragma unroll
  for (int cl = 0; cl < 8; cl++)
    Wl[(size_t)cl * 1024 + tid] = WldsBuf[(size_t)cl * 1024 + tid];

  float c = 0.0f;
  if (t0 == 0) {
    if (tid < 64) hq[tid] = make_uint4(0, 0, 0, 0);
  } else {
    if (tid < 32) hq[tid] = h_state[(size_t)b * 32 + tid];
    if (q == 0)   c = c_state[(size_t)b * 256 + u];
  }
  __syncthreads();

  const float* xzb = xz + (size_t)b * Zdim + u;
  float nx0 = 0, nx1 = 0, nx2 = 0, nx3 = 0;
  if (q == 0) { nx0 = xzb[0]; nx1 = xzb[256]; nx2 = xzb[512]; nx3 = xzb[768]; }
  const uint4* wstr = Wstr + tid;

  for (int tl = 0; tl < Tc; tl++) {
    const int buf = tl & 1;
    const uint4* hb = hq + buf * 32 + q * 8;
    float a0 = 0, a1 = 0, a2 = 0, a3 = 0;

    // issue stream group A (j=6, gates 0..3)
    uint4 sA0 = wstr[0], sA1 = wstr[1024], sA2 = wstr[2048], sA3 = wstr[3072];
    // VGPR phase: j = 0..3  (64 dot2, covers A's L2 latency)
#pragma unroll
    for (int j = 0; j < 4; j++) {
      uint4 h4 = hb[j];
      a0 = dot4(wop[0 * 4 + j], h4, a0);
      a1 = dot4(wop[1 * 4 + j], h4, a1);
      a2 = dot4(wop[2 * 4 + j], h4, a2);
      a3 = dot4(wop[3 * 4 + j], h4, a3);
    }
    // issue stream group B (j=7)
    uint4 sB0 = wstr[4096], sB1 = wstr[5120], sB2 = wstr[6144], sB3 = wstr[7168];
    // LDS phase: j = 4,5
#pragma unroll
    for (int jj = 0; jj < 2; jj++) {
      uint4 h4 = hb[4 + jj];
      uint4 w0 = Wl[(size_t)(jj * 4 + 0) * 1024 + tid];
      uint4 w1 = Wl[(size_t)(jj * 4 + 1) * 1024 + tid];
      uint4 w2 = Wl[(size_t)(jj * 4 + 2) * 1024 + tid];
      uint4 w3 = Wl[(size_t)(jj * 4 + 3) * 1024 + tid];
      a0 = dot4(w0, h4, a0); a1 = dot4(w1, h4, a1);
      a2 = dot4(w2, h4, a2); a3 = dot4(w3, h4, a3);
    }
    // consume streams
    { uint4 h4 = hb[6];
      a0 = dot4(sA0, h4, a0); a1 = dot4(sA1, h4, a1);
      a2 = dot4(sA2, h4, a2); a3 = dot4(sA3, h4, a3); }
    { uint4 h4 = hb[7];
      a0 = dot4(sB0, h4, a0); a1 = dot4(sB1, h4, a1);
      a2 = dot4(sB2, h4, a2); a3 = dot4(sB3, h4, a3); }

    if (q) pp[(size_t)(q - 1) * 256 + u] = make_float4(a0, a1, a2, a3);
    __syncthreads();
    if (!q) {
      float4 p0 = pp[u], p1 = pp[256 + u], p2 = pp[512 + u];
      float z0 = a0 + p0.x + p1.x + p2.x + nx0;
      float z1 = a1 + p0.y + p1.y + p2.y + nx1;
      float z2 = a2 + p0.z + p1.z + p2.z + nx2;
      float z3 = a3 + p0.w + p1.w + p2.w + nx3;
      if (tl + 1 < Tc) {
        const float* xn = xzb + (size_t)(tl + 1) * (Bsz * Zdim);
        nx0 = xn[0]; nx1 = xn[256]; nx2 = xn[512]; nx3 = xn[768];
      }
      float ig = sigm(z0), fg = sigm(z1), gg = tanh_f(z2), og = sigm(z3);
      c = fg * c + ig * gg;
      float hn = og * tanh_f(c);
      int ot = (t0 + tl) - (Tsz - n_out);
      if (ot >= 0) out[((size_t)b * n_out + ot) * UNITSn + u] = hn;
      ((__half*)(hq + (buf ^ 1) * 32))[u] = __float2half(hn);
    }
    __syncthreads();
  }
  if (tid < 32) h_state[(size_t)b * 32 + tid] = hq[(Tc & 1) * 32 + tid];
  if (q == 0)   c_state[(size_t)b * 256 + u] = c;
}

extern "C" void kernel_launch(void* const* d_in, const int* in_sizes, int n_in,
                              void* d_out, int out_size, void* d_ws, size_t ws_size,
                              hipStream_t stream) {
  const float* x    = (const float*)d_in[0];
  const float* U    = (const float*)d_in[1];
  const float* W    = (const float*)d_in[2];
  const float* bias = (const float*)d_in[3];
  float* out = (float*)d_out;
  const int n_out = out_size / (Bsz * UNITSn);   // 32

  uint8_t* ws = (uint8_t*)d_ws;
  uint4* Wop      = (uint4*)ws;                    // 256 KB (16384 uint4)
  uint4* Wlds     = (uint4*)(ws + (256u << 10));   // 128 KB (8192 uint4)
  uint4* Wstr     = (uint4*)(ws + (384u << 10));   // 128 KB (8192 uint4)
  _Float16* UT    = (_Float16*)(ws + (512u << 10));// 512 KB
  uint4* h_state  = (uint4*)(ws + (1024u << 10));  //  32 KB
  float* c_state  = (float*)(ws + (1056u << 10));  //  64 KB
  float* xz       = (float*)(ws + (2u << 20));     // Tc*64*1024 fp32

  int Tc = Tsz;
  while (Tc > 1 && (size_t)(2u << 20) + (size_t)Tc * (Bsz * Zdim) * 4 > ws_size) Tc >>= 1;

  convert_w6<<<dim3(128), dim3(256), 0, stream>>>(W, Wop, Wlds, Wstr);
  convert_u<<<dim3(1024), dim3(256), 0, stream>>>(U, UT);

  const int ldsBytes = (8192 + 64 + 768) * 16;     // 144384 B
  hipFuncSetAttribute((const void*)lstm_chunk,
                      hipFuncAttributeMaxDynamicSharedMemorySize, ldsBytes);

  for (int t0 = 0; t0 < Tsz; t0 += Tc) {
    proj_mfma<<<dim3(4, Tc), dim3(256), 0, stream>>>(x, UT, bias, xz, t0);
    lstm_chunk<<<dim3(Bsz), dim3(1024), ldsBytes, stream>>>(xz, Wop, Wlds, Wstr,
                                                            out, h_state, c_state,
                                                            t0, Tc, n_out);
  }
}

// Round 7
// 2128.654 us; speedup vs baseline: 1.0530x; 1.0530x over previous
//
#include <hip/hip_runtime.h>
#include <hip/hip_fp16.h>
#include <stdint.h>

#define Bsz 64
#define Tsz 1024
#define Dsz 256
#define UNITSn 256
#define Zdim 1024      // 4*UNITS

typedef _Float16 f16x8  __attribute__((ext_vector_type(8)));
typedef float    f32x4  __attribute__((ext_vector_type(4)));

// Guaranteed single-instruction 2-MAC f16 dot with f32 accumulate.
__device__ __forceinline__ float dot2acc(uint32_t w, uint32_t h, float acc) {
  asm("v_dot2_f32_f16 %0, %1, %2, %0" : "+v"(acc) : "v"(w), "v"(h));
  return acc;
}

__device__ __forceinline__ float dot4(const uint4& w, const uint4& h, float acc) {
  acc = dot2acc(w.x, h.x, acc); acc = dot2acc(w.y, h.y, acc);
  acc = dot2acc(w.z, h.z, acc); acc = dot2acc(w.w, h.w, acc);
  return acc;
}

__device__ __forceinline__ float sigm(float x)   { return 1.0f / (1.0f + __expf(-x)); }
__device__ __forceinline__ float tanh_f(float x) { return 1.0f - 2.0f / (__expf(2.0f * x) + 1.0f); }

// U[256][1024] fp32 -> UT[1024][256] f16 (transposed, k-contiguous)
__global__ __launch_bounds__(256) void convert_u(const float* __restrict__ U,
                                                 _Float16* __restrict__ UT) {
  int i = blockIdx.x * 256 + threadIdx.x;   // 262144
  int n = i >> 8, k = i & 255;
  UT[i] = (_Float16)U[(size_t)k * Zdim + n];
}

// W[256][1024] fp32 -> f16-pair layouts for lstm v7 (512 threads, half-K).
// Thread t (half=t>>8, u=t&255), gate g: col=g*256+u, k2 = half*64 + jx*4 + e.
//  slot<40  : Wop [(g*10+jx)*512+t]        jx=0..9   (VGPR, opaque)
//  40..51   : Wlds[((jx-10)*4+g)*512+t]    jx=10..12 (LDS)
//  52..63   : Wstr[((jx-13)*4+g)*512+t]    jx=13..15 (L2 stream)
__global__ __launch_bounds__(256) void convert_w7(const float* __restrict__ W,
                                                  uint4* __restrict__ Wop,
                                                  uint4* __restrict__ Wlds,
                                                  uint4* __restrict__ Wstr) {
  int i = blockIdx.x * 256 + threadIdx.x;   // 32768 uint4
  if (i >= 32768) return;
  int slot = i >> 9, t = i & 511;
  int g, jx, outIdx;
  uint4* dst;
  if (slot < 40)      { g = slot / 10;      jx = slot % 10;        dst = Wop;  outIdx = slot * 512 + t; }
  else if (slot < 52) { int ss = slot - 40; g = ss & 3; jx = 10 + (ss >> 2); dst = Wlds; outIdx = ss * 512 + t; }
  else                { int ss = slot - 52; g = ss & 3; jx = 13 + (ss >> 2); dst = Wstr; outIdx = ss * 512 + t; }
  int col = g * 256 + (t & 255);
  int kbase = (t >> 8) * 64 + jx * 4;
  uint32_t d[4];
#pragma unroll
  for (int e = 0; e < 4; e++) {
    int k2 = kbase + e;
    float w0 = W[(size_t)(2 * k2) * Zdim + col];
    float w1 = W[(size_t)(2 * k2 + 1) * Zdim + col];
    __half2 p = __floats2half2_rn(w0, w1);
    d[e] = __builtin_bit_cast(uint32_t, p);
  }
  dst[outIdx] = make_uint4(d[0], d[1], d[2], d[3]);
}

// xz[(tloc*64+b)*1024+n] = x[b][t][:] @ U[:,n] + bias[n] via f16 MFMA.
__global__ __launch_bounds__(256) void proj_mfma(
    const float* __restrict__ x, const _Float16* __restrict__ UT,
    const float* __restrict__ bias, float* __restrict__ xz, int t0) {
  __shared__ _Float16 Ax[64][40];
  __shared__ _Float16 Ux[256][40];
  const int tid  = threadIdx.x;
  const int w    = tid >> 6, lane = tid & 63;
  const int lr   = lane & 15, kg = lane >> 4;
  const int n0   = blockIdx.x * 256;
  const int tloc = blockIdx.y;
  const int t    = t0 + tloc;
  const int arow = tid >> 2, ak = (tid & 3) * 8;

  f32x4 acc[4][4];
#pragma unroll
  for (int mi = 0; mi < 4; mi++)
#pragma unroll
    for (int ni = 0; ni < 4; ni++) acc[mi][ni] = f32x4{0.f, 0.f, 0.f, 0.f};

  for (int k0 = 0; k0 < Dsz; k0 += 32) {
    const float* xp = x + ((size_t)arow * Tsz + t) * Dsz + k0 + ak;
    float4 p0 = *(const float4*)xp;
    float4 p1 = *(const float4*)(xp + 4);
    const _Float16* up = UT + (size_t)(n0 + tid) * Dsz + k0;
    f16x8 u0 = *(const f16x8*)up;
    f16x8 u1 = *(const f16x8*)(up + 8);
    f16x8 u2 = *(const f16x8*)(up + 16);
    f16x8 u3 = *(const f16x8*)(up + 24);
    __syncthreads();
    f16x8 a8;
    a8[0] = (_Float16)p0.x; a8[1] = (_Float16)p0.y;
    a8[2] = (_Float16)p0.z; a8[3] = (_Float16)p0.w;
    a8[4] = (_Float16)p1.x; a8[5] = (_Float16)p1.y;
    a8[6] = (_Float16)p1.z; a8[7] = (_Float16)p1.w;
    *(f16x8*)&Ax[arow][ak] = a8;
    *(f16x8*)&Ux[tid][0]  = u0;
    *(f16x8*)&Ux[tid][8]  = u1;
    *(f16x8*)&Ux[tid][16] = u2;
    *(f16x8*)&Ux[tid][24] = u3;
    __syncthreads();
    f16x8 af[4], uf[4];
#pragma unroll
    for (int mi = 0; mi < 4; mi++) af[mi] = *(const f16x8*)&Ax[mi * 16 + lr][kg * 8];
#pragma unroll
    for (int ni = 0; ni < 4; ni++) uf[ni] = *(const f16x8*)&Ux[w * 64 + ni * 16 + lr][kg * 8];
#pragma unroll
    for (int mi = 0; mi < 4; mi++)
#pragma unroll
      for (int ni = 0; ni < 4; ni++)
        acc[mi][ni] = __builtin_amdgcn_mfma_f32_16x16x32_f16(af[mi], uf[ni],
                                                             acc[mi][ni], 0, 0, 0);
  }
#pragma unroll
  for (int ni = 0; ni < 4; ni++) {
    int col = n0 + w * 64 + ni * 16 + lr;
    float bs = bias[col];
#pragma unroll
    for (int mi = 0; mi < 4; mi++) {
      f32x4 v = acc[mi][ni];
#pragma unroll
      for (int r = 0; r < 4; r++) {
        int brow = mi * 16 + kg * 4 + r;
        xz[((size_t)tloc * 64 + brow) * Zdim + col] = v[r] + bs;
      }
    }
  }
}

// One WG (512 thr = 8 waves) per batch; STATIC LDS 101 KB forces 1 WG/CU
// = 2 waves/SIMD -> 256-VGPR allocation cap. W: 40 uint4 opaque-VGPR (160 regs)
// + 12 uint4 LDS (96 KB) + 12 uint4 L2-stream (96 KB/step).
__global__ __launch_bounds__(512) void lstm_chunk(
    const float* __restrict__ xz, const uint4* __restrict__ Wop,
    const uint4* __restrict__ WldsBuf, const uint4* __restrict__ Wstr,
    float* __restrict__ out, uint4* __restrict__ h_state,
    float* __restrict__ c_state, int t0, int Tc, int n_out) {
  __shared__ uint4 Wl[12 * 512];   // 96 KB
  __shared__ uint4 hq[2][32];      // 1 KB, packed f16 h double-buffered
  __shared__ float4 pp[256];       // 4 KB, half=1 partials

  const int tid  = threadIdx.x;
  const int b    = blockIdx.x;
  const int half = tid >> 8, u = tid & 255;

  uint4 wop[40];
#pragma unroll
  for (int j = 0; j < 40; j++) wop[j] = Wop[(size_t)j * 512 + tid];
#pragma unroll
  for (int j = 0; j < 40; j++)
    asm volatile("" : "+v"(wop[j].x), "+v"(wop[j].y), "+v"(wop[j].z), "+v"(wop[j].w));
#pragma unroll
  for (int cl = 0; cl < 12; cl++)
    Wl[(size_t)cl * 512 + tid] = WldsBuf[(size_t)cl * 512 + tid];

  float c = 0.0f;
  if (t0 == 0) {
    if (tid < 64) ((uint4*)hq)[tid] = make_uint4(0, 0, 0, 0);
  } else {
    if (tid < 32) ((uint4*)hq)[tid] = h_state[(size_t)b * 32 + tid];
    if (half == 0) c = c_state[(size_t)b * 256 + u];
  }
  __syncthreads();

  const float* xzb = xz + (size_t)b * Zdim + u;
  float nx0 = 0, nx1 = 0, nx2 = 0, nx3 = 0;
  if (half == 0) { nx0 = xzb[0]; nx1 = xzb[256]; nx2 = xzb[512]; nx3 = xzb[768]; }
  const uint4* wstr = Wstr + tid;

  for (int tl = 0; tl < Tc; tl++) {
    const int buf = tl & 1;
    const uint4* hb = hq[buf] + half * 16;
    float a0 = 0, a1 = 0, a2 = 0, a3 = 0;

    // issue stream groups 0,1 (j=13,14)
    uint4 s00 = wstr[0 * 512], s01 = wstr[1 * 512], s02 = wstr[2 * 512], s03 = wstr[3 * 512];
    uint4 s10 = wstr[4 * 512], s11 = wstr[5 * 512], s12 = wstr[6 * 512], s13 = wstr[7 * 512];

    // VGPR phase: j = 0..9 (160 dot2/thread) — covers stream L2 latency
#pragma unroll
    for (int j = 0; j < 10; j++) {
      uint4 h4 = hb[j];
      a0 = dot4(wop[0 * 10 + j], h4, a0);
      a1 = dot4(wop[1 * 10 + j], h4, a1);
      a2 = dot4(wop[2 * 10 + j], h4, a2);
      a3 = dot4(wop[3 * 10 + j], h4, a3);
    }
    // consume stream 0, issue stream 2 (j=15)
    uint4 s20, s21, s22, s23;
    { uint4 h4 = hb[13];
      s20 = wstr[8 * 512]; s21 = wstr[9 * 512]; s22 = wstr[10 * 512]; s23 = wstr[11 * 512];
      a0 = dot4(s00, h4, a0); a1 = dot4(s01, h4, a1);
      a2 = dot4(s02, h4, a2); a3 = dot4(s03, h4, a3); }
    // LDS phase jj=0 (j=10)
    { uint4 h4 = hb[10];
      uint4 w0 = Wl[(size_t)0 * 512 + tid], w1 = Wl[(size_t)1 * 512 + tid];
      uint4 w2 = Wl[(size_t)2 * 512 + tid], w3 = Wl[(size_t)3 * 512 + tid];
      a0 = dot4(w0, h4, a0); a1 = dot4(w1, h4, a1);
      a2 = dot4(w2, h4, a2); a3 = dot4(w3, h4, a3); }
    // consume stream 1
    { uint4 h4 = hb[14];
      a0 = dot4(s10, h4, a0); a1 = dot4(s11, h4, a1);
      a2 = dot4(s12, h4, a2); a3 = dot4(s13, h4, a3); }
    // LDS phase jj=1 (j=11)
    { uint4 h4 = hb[11];
      uint4 w0 = Wl[(size_t)4 * 512 + tid], w1 = Wl[(size_t)5 * 512 + tid];
      uint4 w2 = Wl[(size_t)6 * 512 + tid], w3 = Wl[(size_t)7 * 512 + tid];
      a0 = dot4(w0, h4, a0); a1 = dot4(w1, h4, a1);
      a2 = dot4(w2, h4, a2); a3 = dot4(w3, h4, a3); }
    // consume stream 2
    { uint4 h4 = hb[15];
      a0 = dot4(s20, h4, a0); a1 = dot4(s21, h4, a1);
      a2 = dot4(s22, h4, a2); a3 = dot4(s23, h4, a3); }
    // LDS phase jj=2 (j=12)
    { uint4 h4 = hb[12];
      uint4 w0 = Wl[(size_t)8 * 512 + tid], w1 = Wl[(size_t)9 * 512 + tid];
      uint4 w2 = Wl[(size_t)10 * 512 + tid], w3 = Wl[(size_t)11 * 512 + tid];
      a0 = dot4(w0, h4, a0); a1 = dot4(w1, h4, a1);
      a2 = dot4(w2, h4, a2); a3 = dot4(w3, h4, a3); }

    if (half) pp[u] = make_float4(a0, a1, a2, a3);
    __syncthreads();
    if (!half) {
      float4 q = pp[u];
      float z0 = a0 + q.x + nx0, z1 = a1 + q.y + nx1;
      float z2 = a2 + q.z + nx2, z3 = a3 + q.w + nx3;
      if (tl + 1 < Tc) {
        const float* xn = xzb + (size_t)(tl + 1) * (Bsz * Zdim);
        nx0 = xn[0]; nx1 = xn[256]; nx2 = xn[512]; nx3 = xn[768];
      }
      float ig = sigm(z0), fg = sigm(z1), gg = tanh_f(z2), og = sigm(z3);
      c = fg * c + ig * gg;
      float hn = og * tanh_f(c);
      int ot = (t0 + tl) - (Tsz - n_out);
      if (ot >= 0) out[((size_t)b * n_out + ot) * UNITSn + u] = hn;
      ((__half*)hq[buf ^ 1])[u] = __float2half(hn);
    }
    __syncthreads();
  }
  if (tid < 32) h_state[(size_t)b * 32 + tid] = ((uint4*)hq)[(Tc & 1) * 32 + tid];
  if (half == 0) c_state[(size_t)b * 256 + u] = c;
}

extern "C" void kernel_launch(void* const* d_in, const int* in_sizes, int n_in,
                              void* d_out, int out_size, void* d_ws, size_t ws_size,
                              hipStream_t stream) {
  const float* x    = (const float*)d_in[0];
  const float* U    = (const float*)d_in[1];
  const float* W    = (const float*)d_in[2];
  const float* bias = (const float*)d_in[3];
  float* out = (float*)d_out;
  const int n_out = out_size / (Bsz * UNITSn);   // 32

  uint8_t* ws = (uint8_t*)d_ws;
  uint4* Wop      = (uint4*)ws;                    // 320 KB (20480 uint4)
  uint4* Wlds     = (uint4*)(ws + (320u << 10));   //  96 KB (6144 uint4)
  uint4* Wstr     = (uint4*)(ws + (416u << 10));   //  96 KB (6144 uint4)
  _Float16* UT    = (_Float16*)(ws + (512u << 10));// 512 KB
  uint4* h_state  = (uint4*)(ws + (1024u << 10));  //  32 KB
  float* c_state  = (float*)(ws + (1056u << 10));  //  64 KB
  float* xz       = (float*)(ws + (2u << 20));     // Tc*64*1024 fp32

  int Tc = Tsz;
  while (Tc > 1 && (size_t)(2u << 20) + (size_t)Tc * (Bsz * Zdim) * 4 > ws_size) Tc >>= 1;

  convert_w7<<<dim3(128), dim3(256), 0, stream>>>(W, Wop, Wlds, Wstr);
  convert_u<<<dim3(1024), dim3(256), 0, stream>>>(U, UT);

  for (int t0 = 0; t0 < Tsz; t0 += Tc) {
    proj_mfma<<<dim3(4, Tc), dim3(256), 0, stream>>>(x, UT, bias, xz, t0);
    lstm_chunk<<<dim3(Bsz), dim3(512), 0, stream>>>(xz, Wop, Wlds, Wstr,
                                                    out, h_state, c_state,
                                                    t0, Tc, n_out);
  }
}